// Round 1
// baseline (106.671 us; speedup 1.0000x reference)
//
#include <hip/hip_runtime.h>
#include <hip/hip_bf16.h>

// BlockTopK: x [8192, 8192] fp32, blocks of 4 along dim 1, top-2 per block,
// output {0,1} fp32 mask, same shape.
//
// One thread per 4-element block: float4 load -> 12 compares -> float4 store.
// Tie-break matches jax.lax.top_k (stable: lower index wins on equal values):
//   rank_i = #{ j : v_j > v_i  ||  (v_j == v_i && j < i) };  mask_i = rank_i < 2.

__global__ __launch_bounds__(256) void blocktopk_kernel(
    const float* __restrict__ x, float* __restrict__ out, long long nblocks) {
  long long i = (long long)blockIdx.x * blockDim.x + threadIdx.x;
  const long long stride = (long long)gridDim.x * blockDim.x;
  const float4* __restrict__ xin = reinterpret_cast<const float4*>(x);
  float4* __restrict__ mout = reinterpret_cast<float4*>(out);

  for (; i < nblocks; i += stride) {
    float4 v = xin[i];
    float a0 = v.x, a1 = v.y, a2 = v.z, a3 = v.w;

    // rank of each element under stable descending order (ties -> lower idx)
    // greater(j, i) := (a[j] > a[i]) || (a[j] == a[i] && j < i)
    int r0 = (a1 > a0) + (a2 > a0) + (a3 > a0);
    int r1 = (a0 >= a1) + (a2 > a1) + (a3 > a1);
    int r2 = (a0 >= a2) + (a1 >= a2) + (a3 > a2);
    int r3 = (a0 >= a3) + (a1 >= a3) + (a2 >= a3);

    float4 m;
    m.x = (r0 < 2) ? 1.0f : 0.0f;
    m.y = (r1 < 2) ? 1.0f : 0.0f;
    m.z = (r2 < 2) ? 1.0f : 0.0f;
    m.w = (r3 < 2) ? 1.0f : 0.0f;
    mout[i] = m;
  }
}

extern "C" void kernel_launch(void* const* d_in, const int* in_sizes, int n_in,
                              void* d_out, int out_size, void* d_ws, size_t ws_size,
                              hipStream_t stream) {
  const float* x = (const float*)d_in[0];
  float* out = (float*)d_out;
  const long long n = (long long)in_sizes[0];    // 8192*8192
  const long long nblocks = n / 4;               // 16,777,216

  const int threads = 256;
  // memory-bound: cap grid, grid-stride the rest (256 CU x 8 blocks/CU)
  long long want = (nblocks + threads - 1) / threads;
  int blocks = (int)(want < 2048 ? want : 2048);
  blocktopk_kernel<<<blocks, threads, 0, stream>>>(x, out, nblocks);
}

// Round 3
// 99.354 us; speedup vs baseline: 1.0736x; 1.0736x over previous
//
#include <hip/hip_runtime.h>
#include <hip/hip_bf16.h>

// BlockTopK: x [8192, 8192] fp32, blocks of 4 along dim 1, top-2 per block,
// output {0,1} fp32 mask, same shape.
//
// One thread per 4-element block: float4 load -> 12 compares -> float4 store.
// Streaming, zero-reuse -> non-temporal loads/stores (bypass cache allocation),
// 2x unroll per iteration for memory-level parallelism.
// NOTE: __builtin_nontemporal_* requires a NATIVE vector type (ext_vector_type),
// not HIP's float4 class — hence f32x4 below.
//
// Tie-break matches jax.lax.top_k (stable: lower index wins on equal values):
//   rank_i = #{ j : v_j > v_i  ||  (v_j == v_i && j < i) };  mask_i = rank_i < 2.

typedef float f32x4 __attribute__((ext_vector_type(4)));

__device__ __forceinline__ f32x4 topk_mask4(f32x4 v) {
  float a0 = v.x, a1 = v.y, a2 = v.z, a3 = v.w;
  int r0 = (a1 > a0) + (a2 > a0) + (a3 > a0);
  int r1 = (a0 >= a1) + (a2 > a1) + (a3 > a1);
  int r2 = (a0 >= a2) + (a1 >= a2) + (a3 > a2);
  int r3 = (a0 >= a3) + (a1 >= a3) + (a2 >= a3);
  f32x4 m;
  m.x = (r0 < 2) ? 1.0f : 0.0f;
  m.y = (r1 < 2) ? 1.0f : 0.0f;
  m.z = (r2 < 2) ? 1.0f : 0.0f;
  m.w = (r3 < 2) ? 1.0f : 0.0f;
  return m;
}

__global__ __launch_bounds__(256) void blocktopk_kernel(
    const f32x4* __restrict__ xin, f32x4* __restrict__ mout, long long nblocks) {
  const long long stride = (long long)gridDim.x * blockDim.x;
  long long i = (long long)blockIdx.x * blockDim.x + threadIdx.x;

  // main loop: 2 independent float4 streams in flight per iteration
  for (; i + stride < nblocks; i += 2 * stride) {
    f32x4 v0 = __builtin_nontemporal_load(&xin[i]);
    f32x4 v1 = __builtin_nontemporal_load(&xin[i + stride]);
    f32x4 m0 = topk_mask4(v0);
    f32x4 m1 = topk_mask4(v1);
    __builtin_nontemporal_store(m0, &mout[i]);
    __builtin_nontemporal_store(m1, &mout[i + stride]);
  }
  if (i < nblocks) {
    f32x4 v0 = __builtin_nontemporal_load(&xin[i]);
    __builtin_nontemporal_store(topk_mask4(v0), &mout[i]);
  }
}

extern "C" void kernel_launch(void* const* d_in, const int* in_sizes, int n_in,
                              void* d_out, int out_size, void* d_ws, size_t ws_size,
                              hipStream_t stream) {
  const f32x4* x = (const f32x4*)d_in[0];
  f32x4* out = (f32x4*)d_out;
  const long long n = (long long)in_sizes[0];    // 8192*8192
  const long long nblocks = n / 4;               // 16,777,216 float4 blocks

  const int threads = 256;
  long long want = (nblocks + threads - 1) / threads;
  int blocks = (int)(want < 2048 ? want : 2048); // 8 blocks/CU x 256 CU
  blocktopk_kernel<<<blocks, threads, 0, stream>>>(x, out, nblocks);
}